// Round 2
// baseline (278.678 us; speedup 1.0000x reference)
//
#include <hip/hip_runtime.h>
#include <hip/hip_bf16.h>
#include <math.h>

typedef __attribute__((ext_vector_type(8))) __bf16 bf16x8;
typedef __attribute__((ext_vector_type(4))) __bf16 bf16x4;
typedef __attribute__((ext_vector_type(4))) float f32x4;

#define WSTRIDE 136  // k-stride in bf16 elems: 128 + 8 pad -> only 2-way LDS aliasing (free)

__device__ __forceinline__ float sigmoid_f(float v) {
  return __builtin_amdgcn_rcpf(1.f + __expf(-v));
}
__device__ __forceinline__ float tanh_f(float z) {
  float az = fabsf(z);
  float e = __expf(-2.f * az);
  float t = (1.f - e) * __builtin_amdgcn_rcpf(1.f + e);
  return copysignf(t, z);
}
__device__ __forceinline__ bf16x8 cvt8(float4 a, float4 b) {
  bf16x8 r;
  r[0] = (__bf16)a.x; r[1] = (__bf16)a.y; r[2] = (__bf16)a.z; r[3] = (__bf16)a.w;
  r[4] = (__bf16)b.x; r[5] = (__bf16)b.y; r[6] = (__bf16)b.z; r[7] = (__bf16)b.w;
  return r;
}

// One fused kernel. Grid = 4 N-chunks (low bits) x 128 M-blocks. Each block:
//  - stages its 32-col weight slice (3 gates x {Wx,Wh} = 6 submats of 32n x 128k)
//    fp32->bf16 into LDS ONCE, one __syncthreads,
//  - then streams 32 M-tiles (16 rows each) with zero further barriers.
__global__ __launch_bounds__(512, 4) void augru_kernel(
    const float* __restrict__ x, const float* __restrict__ hp,
    const float* __restrict__ att,
    const float* __restrict__ Wx, const float* __restrict__ bx,
    const float* __restrict__ Wh, const float* __restrict__ bh,
    float* __restrict__ out) {
  __shared__ __bf16 wlds[6 * 32 * WSTRIDE];  // 52,224 B -> 2 blocks/CU

  const int tid  = threadIdx.x;
  const int wave = tid >> 6;    // 0..7
  const int lane = tid & 63;
  const int quad = lane >> 4;
  const int l15  = lane & 15;
  const int nc   = blockIdx.x & 3;   // N-chunk: cols [nc*32, nc*32+32)
  const int mb   = blockIdx.x >> 2;  // 0..127

  // ---- stage weights: 192 LDS rows (s=gate*2+isWh in 0..5, n in 0..31) x 128 k.
  // 6144 float4 chunks, 12 per thread, coalesced.
#pragma unroll
  for (int i = 0; i < 12; ++i) {
    int c    = i * 512 + tid;
    int row  = c >> 5;       // 0..191
    int j    = c & 31;       // float4 index within the 128-k row
    int s    = row >> 5;
    int n    = row & 31;
    int gate = s >> 1;
    const float* src = (s & 1) ? Wh : Wx;
    float4 v = *(const float4*)(src + (gate * 128 + nc * 32 + n) * 128 + j * 4);
    bf16x4 b;
    b[0] = (__bf16)v.x; b[1] = (__bf16)v.y; b[2] = (__bf16)v.z; b[3] = (__bf16)v.w;
    *(bf16x4*)&wlds[(s * 32 + n) * WSTRIDE + j * 4] = b;
  }

  // ---- per-lane biases (column cols[ntL] = nc*32 + ntL*16 + l15)
  float bu[2], br[2], bxh[2], bhh[2];
#pragma unroll
  for (int ntL = 0; ntL < 2; ++ntL) {
    int col = nc * 32 + ntL * 16 + l15;
    bu[ntL]  = bx[col] + bh[col];
    br[ntL]  = bx[128 + col] + bh[128 + col];
    bxh[ntL] = bx[256 + col];
    bhh[ntL] = bh[256 + col];
  }
  __syncthreads();  // the ONLY barrier

  // B-fragment pointer helper: submat s, local n-tile ntL, K-tile kt
  auto B = [&](int s, int ntL, int kt) -> bf16x8 {
    return *(const bf16x8*)&wlds[(s * 32 + ntL * 16 + l15) * WSTRIDE + kt * 32 + quad * 8];
  };

  // ---- main stream: 32 M-tiles per block, 4 per wave, no barriers.
  for (int mt = 0; mt < 4; ++mt) {
    const int tile = mb * 32 + mt * 8 + wave;  // covers 0..4095 exactly
    const int rb   = tile * 16;

    // A fragments straight from global fp32 (dense 16x128 region, coalesced 16B)
    const float* xr = x  + (rb + l15) * 128 + quad * 8;
    const float* hr = hp + (rb + l15) * 128 + quad * 8;
    bf16x8 xf[4], hf[4];
#pragma unroll
    for (int kt = 0; kt < 4; ++kt)
      xf[kt] = cvt8(*(const float4*)(xr + kt * 32), *(const float4*)(xr + kt * 32 + 4));
#pragma unroll
    for (int kt = 0; kt < 4; ++kt)
      hf[kt] = cvt8(*(const float4*)(hr + kt * 32), *(const float4*)(hr + kt * 32 + 4));

    f32x4 aU[2], aR[2], aHX[2], aHH[2];
#pragma unroll
    for (int ntL = 0; ntL < 2; ++ntL) {
      aU[ntL] = (f32x4)0.f; aR[ntL] = (f32x4)0.f;
      aHX[ntL] = (f32x4)0.f; aHH[ntL] = (f32x4)0.f;
    }

#pragma unroll
    for (int ntL = 0; ntL < 2; ++ntL) {
#pragma unroll
      for (int kt = 0; kt < 4; ++kt) {
        aU[ntL]  = __builtin_amdgcn_mfma_f32_16x16x32_bf16(xf[kt], B(0, ntL, kt), aU[ntL], 0, 0, 0);
        aU[ntL]  = __builtin_amdgcn_mfma_f32_16x16x32_bf16(hf[kt], B(1, ntL, kt), aU[ntL], 0, 0, 0);
        aR[ntL]  = __builtin_amdgcn_mfma_f32_16x16x32_bf16(xf[kt], B(2, ntL, kt), aR[ntL], 0, 0, 0);
        aR[ntL]  = __builtin_amdgcn_mfma_f32_16x16x32_bf16(hf[kt], B(3, ntL, kt), aR[ntL], 0, 0, 0);
        aHX[ntL] = __builtin_amdgcn_mfma_f32_16x16x32_bf16(xf[kt], B(4, ntL, kt), aHX[ntL], 0, 0, 0);
        aHH[ntL] = __builtin_amdgcn_mfma_f32_16x16x32_bf16(hf[kt], B(5, ntL, kt), aHH[ntL], 0, 0, 0);
      }
    }

    // ---- fused epilogue (C-layout: col = l15, row = quad*4 + rr)
    float att4[4];
#pragma unroll
    for (int rr = 0; rr < 4; ++rr) att4[rr] = att[rb + quad * 4 + rr];
#pragma unroll
    for (int ntL = 0; ntL < 2; ++ntL) {
      const int col = nc * 32 + ntL * 16 + l15;
#pragma unroll
      for (int rr = 0; rr < 4; ++rr) {
        const int row = rb + quad * 4 + rr;
        float u  = sigmoid_f(aU[ntL][rr] + bu[ntL]);
        float r  = sigmoid_f(aR[ntL][rr] + br[ntL]);
        float ht = tanh_f(aHX[ntL][rr] + bxh[ntL] + r * (aHH[ntL][rr] + bhh[ntL]));
        float ua = att4[rr] * u;
        float h0 = hp[row * 128 + col];
        out[row * 128 + col] = fmaf(ua, ht - h0, h0);
      }
    }
  }
}

extern "C" void kernel_launch(void* const* d_in, const int* in_sizes, int n_in,
                              void* d_out, int out_size, void* d_ws, size_t ws_size,
                              hipStream_t stream) {
  const float* x   = (const float*)d_in[0];
  const float* hpv = (const float*)d_in[1];
  const float* att = (const float*)d_in[2];
  const float* Wx  = (const float*)d_in[3];
  const float* bx  = (const float*)d_in[4];
  const float* Wh  = (const float*)d_in[5];
  const float* bh  = (const float*)d_in[6];
  float* out = (float*)d_out;

  augru_kernel<<<512, 512, 0, stream>>>(x, hpv, att, Wx, bx, Wh, bh, out);
}

// Round 3
// 136.007 us; speedup vs baseline: 2.0490x; 2.0490x over previous
//
#include <hip/hip_runtime.h>
#include <hip/hip_bf16.h>
#include <math.h>

typedef __attribute__((ext_vector_type(8))) __bf16 bf16x8;
typedef __attribute__((ext_vector_type(4))) __bf16 bf16x4;
typedef __attribute__((ext_vector_type(4))) float f32x4;

#define AST 136  // LDS A-tile row stride in bf16 elems (128+8 pad -> 2-way bank aliasing = free)

__device__ __forceinline__ float sigmoid_f(float v) {
  return __builtin_amdgcn_rcpf(1.f + __expf(-v));
}
__device__ __forceinline__ float tanh_f(float z) {
  float az = fabsf(z);
  float e = __expf(-2.f * az);
  float t = (1.f - e) * __builtin_amdgcn_rcpf(1.f + e);
  return copysignf(t, z);
}
__device__ __forceinline__ bf16x8 cvt8(float4 a, float4 b) {
  bf16x8 r;
  r[0] = (__bf16)a.x; r[1] = (__bf16)a.y; r[2] = (__bf16)a.z; r[3] = (__bf16)a.w;
  r[4] = (__bf16)b.x; r[5] = (__bf16)b.y; r[6] = (__bf16)b.z; r[7] = (__bf16)b.w;
  return r;
}
__device__ __forceinline__ bf16x4 cvt4(float4 a) {
  bf16x4 r;
  r[0] = (__bf16)a.x; r[1] = (__bf16)a.y; r[2] = (__bf16)a.z; r[3] = (__bf16)a.w;
  return r;
}

// Block = 512 threads = 8 waves. Wave w owns output cols [16w, 16w+16) and keeps
// ALL its weights (6 submats x 4 K-tiles) in 96 VGPRs. Block owns full 128-col rows
// -> compulsory-only reads, full-line writes. x/h tiles stream through a
// double-buffered LDS stage (one barrier per 16-row tile).
__global__ __launch_bounds__(512, 2) void augru_kernel(
    const float* __restrict__ x, const float* __restrict__ hp,
    const float* __restrict__ att,
    const float* __restrict__ Wx, const float* __restrict__ bx,
    const float* __restrict__ Wh, const float* __restrict__ bh,
    float* __restrict__ out) {
  __shared__ __bf16 alds[2][2][16 * AST];  // [buf][mat(x,h)][row*AST + k] = 17,408 B

  const int tid  = threadIdx.x;
  const int wave = tid >> 6;
  const int lane = tid & 63;
  const int quad = lane >> 4;
  const int l15  = lane & 15;
  const int col  = wave * 16 + l15;     // this lane's output column

  // ---- persistent B-fragments: mat m = gate*2 + (0:Wx,1:Wh), gates u=0,r=1,h=2.
  // B-frag layout for 16x16x32: lane(l15,quad) holds W[n=col][k=kt*32+quad*8 ..+8].
  bf16x8 wf[6][4];
#pragma unroll
  for (int m = 0; m < 6; ++m) {
    const float* src = (m & 1) ? Wh : Wx;
    const float* wr  = src + ((m >> 1) * 128 + col) * 128 + quad * 8;
#pragma unroll
    for (int kt = 0; kt < 4; ++kt)
      wf[m][kt] = cvt8(*(const float4*)(wr + kt * 32), *(const float4*)(wr + kt * 32 + 4));
  }

  // ---- per-lane biases
  const float bu_  = bx[col] + bh[col];
  const float br_  = bx[128 + col] + bh[128 + col];
  const float bxh_ = bx[256 + col];
  const float bhh_ = bh[256 + col];

  // ---- staging map: thread stages one x-float4 and one h-float4 per tile:
  // row = tid>>5 (0..15), j = tid&31 (float4 within the 128-col row)
  const int srow = tid >> 5;
  const int sj   = tid & 31;
  const long sgoff = (long)srow * 128 + sj * 4;  // + tile_row_base*128

  const int T = 8;                         // tiles per block
  const int tile0 = blockIdx.x * T;        // 512 blocks * 8 tiles = 4096 = 65536/16

  // prefetch tile 0
  float4 xv = *(const float4*)(x  + (long)tile0 * 16 * 128 + sgoff);
  float4 hv = *(const float4*)(hp + (long)tile0 * 16 * 128 + sgoff);

  for (int t = 0; t < T; ++t) {
    const int rb = (tile0 + t) * 16;

    // commit staged regs to LDS buf[t&1]
    *(bf16x4*)&alds[t & 1][0][srow * AST + sj * 4] = cvt4(xv);
    *(bf16x4*)&alds[t & 1][1][srow * AST + sj * 4] = cvt4(hv);

    // prefetch next tile (global loads in flight across the barrier + MFMA)
    if (t + 1 < T) {
      xv = *(const float4*)(x  + (long)(rb + 16) * 128 + sgoff);
      hv = *(const float4*)(hp + (long)(rb + 16) * 128 + sgoff);
    }

    __syncthreads();  // buf[t&1] visible to all waves

    // A-fragments from LDS: A[m=l15][k=quad*8+j]
    bf16x8 xf[4], hf[4];
#pragma unroll
    for (int kt = 0; kt < 4; ++kt) {
      xf[kt] = *(const bf16x8*)&alds[t & 1][0][l15 * AST + kt * 32 + quad * 8];
      hf[kt] = *(const bf16x8*)&alds[t & 1][1][l15 * AST + kt * 32 + quad * 8];
    }

    f32x4 aU = (f32x4)0.f, aR = (f32x4)0.f, aHX = (f32x4)0.f, aHH = (f32x4)0.f;
#pragma unroll
    for (int kt = 0; kt < 4; ++kt) {
      aU  = __builtin_amdgcn_mfma_f32_16x16x32_bf16(xf[kt], wf[0][kt], aU, 0, 0, 0);
      aU  = __builtin_amdgcn_mfma_f32_16x16x32_bf16(hf[kt], wf[1][kt], aU, 0, 0, 0);
      aR  = __builtin_amdgcn_mfma_f32_16x16x32_bf16(xf[kt], wf[2][kt], aR, 0, 0, 0);
      aR  = __builtin_amdgcn_mfma_f32_16x16x32_bf16(hf[kt], wf[3][kt], aR, 0, 0, 0);
      aHX = __builtin_amdgcn_mfma_f32_16x16x32_bf16(xf[kt], wf[4][kt], aHX, 0, 0, 0);
      aHH = __builtin_amdgcn_mfma_f32_16x16x32_bf16(hf[kt], wf[5][kt], aHH, 0, 0, 0);
    }

    // ---- fused epilogue. C layout: col = l15-part, row = quad*4 + rr.
#pragma unroll
    for (int rr = 0; rr < 4; ++rr) {
      const int row = rb + quad * 4 + rr;
      float u  = sigmoid_f(aU[rr] + bu_);
      float r  = sigmoid_f(aR[rr] + br_);
      float ht = tanh_f(aHX[rr] + bxh_ + r * (aHH[rr] + bhh_));
      float ua = att[row] * u;
      float h0 = hp[(long)row * 128 + col];
      out[(long)row * 128 + col] = fmaf(ua, ht - h0, h0);
    }
  }
}

extern "C" void kernel_launch(void* const* d_in, const int* in_sizes, int n_in,
                              void* d_out, int out_size, void* d_ws, size_t ws_size,
                              hipStream_t stream) {
  const float* x   = (const float*)d_in[0];
  const float* hpv = (const float*)d_in[1];
  const float* att = (const float*)d_in[2];
  const float* Wx  = (const float*)d_in[3];
  const float* bx  = (const float*)d_in[4];
  const float* Wh  = (const float*)d_in[5];
  const float* bh  = (const float*)d_in[6];
  float* out = (float*)d_out;

  augru_kernel<<<512, 512, 0, stream>>>(x, hpv, att, Wx, bx, Wh, bh, out);
}